// Round 4
// baseline (366.744 us; speedup 1.0000x reference)
//
#include <hip/hip_runtime.h>
#include <hip/hip_bf16.h>
#include <stdint.h>
#include <type_traits>

// ---------------------------------------------------------------------------
// MultiExpertMoELayer: opcode-routed 2-stage FFN chain.
//   op = argmax(x[0,0,0:8]);  for e in 0..1: x = gelu(x@W1[op,e]+b1)@W2[op,e]+b2
// Round 3 changes vs round 2:
//   1. Full-tile prefetch issued as one cluster at tile top -> every
//      global_load_lds gets a full K-tile (~4 phases) of latency cover;
//      counted vmcnt(S) at the boundary only (T4).
//   2. m201 double-barrier phases: {ds_read -> SBAR -> lgkm0 -> setprio MFMA
//      -> SBAR}, 4 phases/K-tile, 16 (or 8) MFMA per phase.
//   3. GEMM2 (BN=128) wave grid 4M x 2N (cuts per-K-tile LDS traffic
//      160KB -> 128KB; serial-phase bound 1040 -> ~1380 TF).
// Numerics identical to rounds 0-2 (same staging swizzle, same MFMA order):
// absmax canary = 0.01171875.
// ---------------------------------------------------------------------------

typedef __attribute__((ext_vector_type(8))) short short8;   // 8 x bf16 (4 VGPR)
typedef __attribute__((ext_vector_type(4))) float f32x4;    // MFMA accum

#define LGKM0  asm volatile("s_waitcnt lgkmcnt(0)" ::: "memory")
#define SBAR   __builtin_amdgcn_s_barrier()
#define SCHEDB __builtin_amdgcn_sched_barrier(0)

template<int VM> __device__ __forceinline__ void wait_vm() {
  if constexpr (VM == 8)      asm volatile("s_waitcnt vmcnt(8)" ::: "memory");
  else if constexpr (VM == 6) asm volatile("s_waitcnt vmcnt(6)" ::: "memory");
  else                        asm volatile("s_waitcnt vmcnt(0)" ::: "memory");
}

__device__ __forceinline__ unsigned short f2bf(float f) {
  union { float f; uint32_t u; } v; v.f = f;
  return (unsigned short)((v.u + 0x7fffu + ((v.u >> 16) & 1u)) >> 16);  // RNE
}

// jax.nn.gelu(approximate=True): 0.5x(1+tanh(sqrt(2/pi)(x+0.044715x^3)))
__device__ __forceinline__ float gelu_tanh(float x) {
  float u = 0.7978845608028654f * (x + 0.044715f * x * x * x);
  float e = __expf(2.0f * u);
  float t = 1.0f - 2.0f / (e + 1.0f);   // tanh(u), safe at +/-inf
  return 0.5f * x * (1.0f + t);
}

__device__ __forceinline__ void gload_lds16(const void* g, void* l) {
  __builtin_amdgcn_global_load_lds(
      (const __attribute__((address_space(1))) void*)g,
      (__attribute__((address_space(3))) void*)l, 16, 0, 0);
}

// --------------------------- routing ---------------------------------------
__global__ void route_kernel(const float* __restrict__ x, int* __restrict__ op_out) {
  if (threadIdx.x == 0) {
    int best = 0; float bv = x[0];
    for (int i = 1; i < 8; ++i) { float v = x[i]; if (v > bv) { bv = v; best = i; } }
    *op_out = best;   // first-max wins, matches jnp.argmax
  }
}

// --------------------------- converts --------------------------------------
__global__ void cvt_x_kernel(const float* __restrict__ x, unsigned short* __restrict__ xb, int n4) {
  int i = blockIdx.x * blockDim.x + threadIdx.x;
  if (i >= n4) return;
  float4 v = ((const float4*)x)[i];
  ushort4 o; o.x = f2bf(v.x); o.y = f2bf(v.y); o.z = f2bf(v.z); o.w = f2bf(v.w);
  ((ushort4*)xb)[i] = o;
}

// in: fp32 [R][C] (opcode/expert-selected at runtime) -> out: bf16 [C][R]
__global__ void transpose_cvt_kernel(const float* __restrict__ Wbase,
                                     unsigned short* __restrict__ outb,
                                     const int* __restrict__ op_ptr,
                                     int R, int C, int expert) {
  __shared__ float tile[64][65];
  const int op = *op_ptr;
  const float* W = Wbase + ((size_t)op * 2 + (size_t)expert) * (size_t)R * (size_t)C;
  const int tr = blockIdx.y, tc = blockIdx.x;
  const int t = threadIdx.x;
  {
    const int r  = t >> 2;
    const int c0 = (t & 3) * 16;
    const float* src = W + (size_t)(tr * 64 + r) * C + tc * 64 + c0;
#pragma unroll
    for (int j = 0; j < 16; j += 4) {
      float4 v = *(const float4*)(src + j);
      tile[r][c0 + j]     = v.x;
      tile[r][c0 + j + 1] = v.y;
      tile[r][c0 + j + 2] = v.z;
      tile[r][c0 + j + 3] = v.w;
    }
  }
  __syncthreads();
  {
    const int c  = t >> 2;
    const int r0 = (t & 3) * 16;
    unsigned short* dst = outb + (size_t)(tc * 64 + c) * R + tr * 64 + r0;
#pragma unroll
    for (int j = 0; j < 16; j += 4) {
      ushort4 o;
      o.x = f2bf(tile[r0 + j][c]);
      o.y = f2bf(tile[r0 + j + 1][c]);
      o.z = f2bf(tile[r0 + j + 2][c]);
      o.w = f2bf(tile[r0 + j + 3][c]);
      *(ushort4*)(dst + j) = o;
    }
  }
}

// --------------------------- phase-split GEMM -------------------------------
// C = A @ Bt^T + bias [,gelu].  A: [M][K] bf16, Bt: [N][K] bf16.
// BM=256, BN=BN64*64, BK=64. 8 waves in WR x WC grid.
// LDS per buffer: A [256][64] + B [BN][64] bf16; 16B chunk c of row r stored
// at c ^ (r&7) (both-sides swizzle with pre-swizzled staging source).

template<int BN64>
__device__ __forceinline__ void stage_tile_all(
    const unsigned short* __restrict__ Ab,
    const unsigned short* __restrict__ Bb,
    int K, int kb, short* __restrict__ dst, int tid) {
  constexpr int ABK = 256 * 64;   // shorts in A region
#pragma unroll
  for (int j = 0; j < 4; ++j) {          // A: 4 instrs cover 256x64
    const int ci = j * 512 + tid;
    const int row = ci >> 3;
    const int gc = (ci & 7) ^ (row & 7);
    gload_lds16(Ab + (size_t)row * K + kb + gc * 8, dst + ci * 8);
  }
#pragma unroll
  for (int j = 0; j < BN64; ++j) {       // B: BN64 instrs cover BN x 64
    const int cj = j * 512 + tid;
    const int row = cj >> 3;
    const int gc = (cj & 7) ^ (row & 7);
    gload_lds16(Bb + (size_t)row * K + kb + gc * 8, dst + ABK + cj * 8);
  }
}

template<int BN64, int WR, bool GELU, typename OUT_T>
__global__ __launch_bounds__(512, 2) void gemm_8ph(
    const unsigned short* __restrict__ A,
    const unsigned short* __restrict__ Bt,
    const float* __restrict__ bias_base,     // [8][2][N]
    const int* __restrict__ op_ptr, int expert,
    OUT_T* __restrict__ Cout, int M, int N, int K, int nbn)
{
  constexpr int BM = 256, BK = 64;
  constexpr int BN = BN64 * 64;
  constexpr int WC = 8 / WR;              // wave grid WR x WC
  constexpr int MR = BM / 16 / WR;        // M-frags per wave (8 or 4)
  constexpr int NR = BN / 16 / WC;        // N-frags per wave (4)
  constexpr int MH = MR / 2;              // frags per M-half phase
  constexpr int S  = 4 + BN64;            // stage instrs per K-tile
  constexpr int BUF = (BM + BN) * BK;     // shorts per double-buffer half
  __shared__ short smem[2 * BUF];

  const int tid  = threadIdx.x;
  const int wid  = tid >> 6, lane = tid & 63;
  const int wm   = wid / WC, wn = wid % WC;
  const int lq   = lane >> 4, lr = lane & 15;

  // XCD-aware bijective swizzle (nwg % 8 == 0), bm-major within an XCD chunk
  const int nwg = gridDim.x;
  const int id  = blockIdx.x;
  const int s   = (id & 7) * (nwg >> 3) + (id >> 3);
  const int bm  = s / nbn, bn = s % nbn;

  const unsigned short* Ab = A  + (size_t)bm * BM * K;
  const unsigned short* Bb = Bt + (size_t)bn * BN * K;

  f32x4 acc[MR][NR] = {};

  // prologue: stage all of K-tile 0 into buffer 0
  stage_tile_all<BN64>(Ab, Bb, K, 0, smem, tid);

  const int nkt = K / BK;
  for (int t = 0; t < nkt; ++t) {
    short* cur = smem + (t & 1) * BUF;
    short* nxt = smem + ((t + 1) & 1) * BUF;

    // tile top: issue ALL of tile t+1's stages (full-tile latency cover),
    // then counted wait for tile t's loads only (T4: t+1 stays in flight).
    if (t + 1 < nkt) { stage_tile_all<BN64>(Ab, Bb, K, (t + 1) * BK, nxt, tid); wait_vm<S>(); }
    else             { wait_vm<0>(); }
    SBAR; SCHEDB;

    const char* cA = (const char*)cur;
    const char* cB = (const char*)(cur + BM * BK);
#pragma unroll
    for (int ks = 0; ks < 2; ++ks) {
      short8 bf[NR];
#pragma unroll
      for (int mh = 0; mh < 2; ++mh) {
        // --- phase (ks, mh): ds_read cluster ---
        short8 af[MH];
#pragma unroll
        for (int mm = 0; mm < MH; ++mm) {
          const int ra = wm * (BM / WR) + (mh * MH + mm) * 16 + lr;
          const int ch = ((ks << 2) | lq) ^ (ra & 7);
          af[mm] = *(const short8*)(cA + ra * 128 + ch * 16);
        }
        if (mh == 0) {
#pragma unroll
          for (int n = 0; n < NR; ++n) {
            const int rb = wn * (BN / WC) + n * 16 + lr;
            const int ch = ((ks << 2) | lq) ^ (rb & 7);
            bf[n] = *(const short8*)(cB + rb * 128 + ch * 16);
          }
        }
        SBAR;                       // all waves issued reads (m201 order)
        LGKM0; SCHEDB;              // rule 18: sched_barrier after lgkmcnt
        __builtin_amdgcn_s_setprio(1);
#pragma unroll
        for (int mm = 0; mm < MH; ++mm)
#pragma unroll
          for (int n = 0; n < NR; ++n)
            acc[mh * MH + mm][n] = __builtin_amdgcn_mfma_f32_16x16x32_bf16(
                af[mm], bf[n], acc[mh * MH + mm][n], 0, 0, 0);
        __builtin_amdgcn_s_setprio(0);
        SCHEDB; SBAR;
      }
    }
  }

  // Epilogue: C/D layout col=lane&15, row=(lane>>4)*4+reg [m89-verified]
  const int op = *op_ptr;
  const float* bias = bias_base + ((size_t)op * 2 + (size_t)expert) * (size_t)N;
#pragma unroll
  for (int f = 0; f < MR; ++f) {
    const int grow0 = bm * BM + wm * (BM / WR) + f * 16 + lq * 4;
#pragma unroll
    for (int n = 0; n < NR; ++n) {
      const int gcol = bn * BN + wn * (BN / WC) + n * 16 + lr;
      const float bv = bias[gcol];
#pragma unroll
      for (int r = 0; r < 4; ++r) {
        float v = acc[f][n][r] + bv;
        if constexpr (GELU) v = gelu_tanh(v);
        const size_t off = (size_t)(grow0 + r) * N + gcol;
        if constexpr (std::is_same<OUT_T, float>::value) Cout[off] = v;
        else Cout[off] = f2bf(v);
      }
    }
  }
}

// --------------------------- launcher ---------------------------------------
extern "C" void kernel_launch(void* const* d_in, const int* in_sizes, int n_in,
                              void* d_out, int out_size, void* d_ws, size_t ws_size,
                              hipStream_t stream) {
  const float* x  = (const float*)d_in[0];
  const float* W1 = (const float*)d_in[1];   // [8][2][1024][4096]
  const float* b1 = (const float*)d_in[2];   // [8][2][4096]
  const float* W2 = (const float*)d_in[3];   // [8][2][4096][1024]
  const float* b2 = (const float*)d_in[4];   // [8][2][1024]
  float* out = (float*)d_out;

  const int D = 1024, F = 4096, M = 8192;    // M = B*S = 4*2048

  // ws layout: [op int, pad 1KB][xb 16.8MB][w1t 16.8MB][w2t 16.8MB][h 67.1MB]
  char* ws = (char*)d_ws;
  int* op_ptr = (int*)ws;
  unsigned short* xb  = (unsigned short*)(ws + 1024);
  unsigned short* w1t = (unsigned short*)(ws + 1024 + (size_t)M * D * 2);
  unsigned short* w2t = (unsigned short*)(ws + 1024 + (size_t)M * D * 2 + (size_t)2 * D * F * 2);
  unsigned short* h   = (unsigned short*)(ws + 1024 + (size_t)M * D * 2 + (size_t)4 * D * F * 2);
  unsigned short* x1b = (unsigned short*)d_out;  // stage-0 output parked in d_out

  route_kernel<<<1, 64, 0, stream>>>(x, op_ptr);
  cvt_x_kernel<<<(M * D / 4 + 255) / 256, 256, 0, stream>>>(x, xb, M * D / 4);

  for (int e = 0; e < 2; ++e) {
    // W1[op,e]: [D][F] -> w1t[e]: [F][D]
    transpose_cvt_kernel<<<dim3(F / 64, D / 64), 256, 0, stream>>>(W1, w1t + (size_t)e * F * D, op_ptr, D, F, e);
    // W2[op,e]: [F][D] -> w2t[e]: [D][F]
    transpose_cvt_kernel<<<dim3(D / 64, F / 64), 256, 0, stream>>>(W2, w2t + (size_t)e * D * F, op_ptr, F, D, e);
  }

  // GEMM1: M=8192, N=4096, K=1024 -> BM=256, BN=256, waves 2Mx4N, grid 512
  // GEMM2: M=8192, N=1024, K=4096 -> BM=256, BN=128, waves 4Mx2N, grid 256
  // expert 0
  gemm_8ph<4, 2, true,  unsigned short><<<(M/256)*(F/256), 512, 0, stream>>>(xb,  w1t,                 b1, op_ptr, 0, h,   M, F, D, F/256);
  gemm_8ph<2, 4, false, unsigned short><<<(M/256)*(D/128), 512, 0, stream>>>(h,   w2t,                 b2, op_ptr, 0, x1b, M, D, F, D/128);
  // expert 1
  gemm_8ph<4, 2, true,  unsigned short><<<(M/256)*(F/256), 512, 0, stream>>>(x1b, w1t + (size_t)F * D, b1, op_ptr, 1, h,   M, F, D, F/256);
  gemm_8ph<2, 4, false, float         ><<<(M/256)*(D/128), 512, 0, stream>>>(h,   w2t + (size_t)D * F, b2, op_ptr, 1, out, M, D, F, D/128);
}